// Round 5
// baseline (432.190 us; speedup 1.0000x reference)
//
#include <hip/hip_runtime.h>
#include <math.h>

#define KK 128
#define TT 512
#define BB 512
#define TAG_START 126
#define TAG_STOP 127

typedef float v4f __attribute__((ext_vector_type(4)));

// x layout: chunk c (cols 8c..8c+7) at float offset 8c + 4*(c>>2); tag j at
// XI(j) = j + 4*(j>>5). 16 b128 chunk addrs read 256B distinct -> structural
// 2-cycle LDS return (16 addrs x 4 banks > 32 banks); not fixable, not the
// limiter. Max XI(127)=139.
#define XI(j) ((j) + (((j) >> 5) << 2))

// DPP move (VALU pipe): quad_perm xor1=0xB1 [1,0,3,2], xor2=0x4E [2,3,0,1];
// row_ror:4=0x124, row_ror:8=0x128 (rotation within 16-lane DPP rows).
template <int CTRL>
__device__ __forceinline__ float dpp_movf(float x) {
    return __int_as_float(
        __builtin_amdgcn_update_dpp(0, __float_as_int(x), CTRL, 0xF, 0xF, true));
}

// lgkmcnt-only barrier: LDS handoff needs lgkm drain; global prefetch loads
// stay in flight (per-thread register dests, no cross-thread hazard).
#define STEP_BARRIER() asm volatile("s_waitcnt lgkmcnt(0)\n\ts_barrier" ::: "memory")

// ws layout (1536 words, identical to verified R3):
//   floats fwd [0,512), gold [512,1024); ints order [1024,1536)

// Descending-length rank: order[r] = seq index with rank r.
__global__ __launch_bounds__(512) void order_kernel(const int* __restrict__ lengths,
                                                    int* __restrict__ order) {
    __shared__ int L[BB];
    int tid = threadIdx.x;
    L[tid] = lengths[tid];
    __syncthreads();
    int mylen = L[tid];
    int r = 0;
    for (int i = 0; i < BB; i++) {
        int li = L[i];
        r += (li > mylen) || (li == mylen && i < tid);
    }
    order[r] = tid;
}

// Blocks 0..255: forward recursion for TWO sequences (ranks 2i, 2i+1 — LPT
// pairing, len0 >= len1). R4 showed the limiter is the ~850cy per-step serial
// chain (barrier + LDS round-trip + reduce), paid once per sequence per block;
// balancing schedules didn't help. Sharing one block (and its one barrier +
// one in-register E, which depends only on trans) between 2 sequences halves
// the per-sequence chain cost: both dots live in one basic block so their
// LDS/fmaf/DPP latencies interleave.
// Blocks 256..767: gold score for seq blockIdx-256.
__global__ __launch_bounds__(512, 4) void fused_kernel(
    const float* __restrict__ feats, const float* __restrict__ trans,
    const int* __restrict__ tags, const int* __restrict__ lengths,
    const int* __restrict__ order,
    float* __restrict__ fwd_out, float* __restrict__ gold_out) {
    int tid = threadIdx.x;
    int w = tid >> 6;
    int l = tid & 63;

    if (blockIdx.x < BB / 2) {
        // ---------------- forward path (2 sequences) ----------------
        int b0i = order[2 * blockIdx.x];
        int b1i = order[2 * blockIdx.x + 1];

        __shared__ __align__(16) float xs[2][2][160];   // [seq][dbuf][slot]
        __shared__ float As[2][2];                      // [seq][dbuf]
        __shared__ float redm[8], reds[8];

        // lane geometry
        int g = (l >> 4) & 3;
        int c = l & 15;
        bool b0 = (l & 1) != 0;
        bool b1 = (l & 2) != 0;
        int row_mine = 16 * w + 4 * g + 2 * (l & 1) + ((l >> 1) & 1);
        int xoff = 8 * c + 4 * (c >> 2);   // float offset of my x chunk
        int xw = XI(row_mine);             // my x write slot
        bool writer = (l & 12) == 0;       // one replica lane per row

        // pin E block (4 rows x 8 cols) via volatile asm loads; E is shared
        // by both sequences (depends only on trans).
        v4f tv[8];
#pragma unroll
        for (int r = 0; r < 4; r++) {
            const float* tp = trans + (16 * w + 4 * g + r) * KK + 8 * c;
            asm volatile("global_load_dwordx4 %0, %1, off"
                         : "=v"(tv[2 * r]) : "v"(tp));
            asm volatile("global_load_dwordx4 %0, %1, off"
                         : "=v"(tv[2 * r + 1]) : "v"(tp + 4));
        }
        int len0 = lengths[b0i];
        int len1 = lengths[b1i];
        const float* fbr0 = feats + (size_t)b0i * TT * KK + row_mine;
        const float* fbr1 = feats + (size_t)b1i * TT * KK + row_mine;
        asm volatile("s_waitcnt vmcnt(0)"
                     : "+v"(tv[0]), "+v"(tv[1]), "+v"(tv[2]), "+v"(tv[3]),
                       "+v"(tv[4]), "+v"(tv[5]), "+v"(tv[6]), "+v"(tv[7]));

        // per-row full-row maxes (reduce across the 16 chunk lanes)
        float Mj0, Mj1, Mj2, Mj3;
        {
            float m[4];
#pragma unroll
            for (int r = 0; r < 4; r++) {
                v4f aL = tv[2 * r], aH = tv[2 * r + 1];
                float mm = fmaxf(fmaxf(fmaxf(aL.x, aL.y), fmaxf(aL.z, aL.w)),
                                 fmaxf(fmaxf(aH.x, aH.y), fmaxf(aH.z, aH.w)));
#pragma unroll
                for (int off = 1; off <= 8; off <<= 1)
                    mm = fmaxf(mm, __shfl_xor(mm, off));
                m[r] = mm;
            }
            Mj0 = m[0]; Mj1 = m[1]; Mj2 = m[2]; Mj3 = m[3];
        }
        float Mj_mine = b0 ? (b1 ? Mj3 : Mj2) : (b1 ? Mj1 : Mj0);

        float Erow[32];
#pragma unroll
        for (int r = 0; r < 4; r++) {
            float mr = (r == 0) ? Mj0 : (r == 1) ? Mj1 : (r == 2) ? Mj2 : Mj3;
            Erow[8 * r + 0] = __expf(tv[2 * r].x - mr);
            Erow[8 * r + 1] = __expf(tv[2 * r].y - mr);
            Erow[8 * r + 2] = __expf(tv[2 * r].z - mr);
            Erow[8 * r + 3] = __expf(tv[2 * r].w - mr);
            Erow[8 * r + 4] = __expf(tv[2 * r + 1].x - mr);
            Erow[8 * r + 5] = __expf(tv[2 * r + 1].y - mr);
            Erow[8 * r + 6] = __expf(tv[2 * r + 1].z - mr);
            Erow[8 * r + 7] = __expf(tv[2 * r + 1].w - mr);
        }

        // init x(0) = exp(alpha0 - 0) for both sequences
        if (writer) {
            float x0 = (row_mine == TAG_START) ? 1.0f : 0.0f;
            xs[0][0][xw] = x0;
            xs[1][0][xw] = x0;
        }
        if (tid == 0) {
            As[0][0] = 0.f; As[0][1] = 0.f;
            As[1][0] = 0.f; As[1][1] = 0.f;
        }

        float alpha0 = 0.f, A0 = 0.f;
        float alpha1 = 0.f, A1 = 0.f;
        // rolling 8-deep emission prefetch, both sequences
        float emb0[8], emb1[8];
#pragma unroll
        for (int d = 0; d < 8; d++) {
            int tf0 = (d < len0) ? d : (len0 - 1);
            int tf1 = (d < len1) ? d : (len1 - 1);
            emb0[d] = fbr0[(size_t)tf0 * KK];
            emb1[d] = fbr1[(size_t)tf1 * KK];
        }
        __syncthreads();

        int tmax = (len0 + 7) & ~7;   // len0 >= len1
        for (int t0 = 0; t0 < tmax; t0 += 8) {
#pragma unroll
            for (int d = 0; d < 8; d++) {
                int t = t0 + d;
                if (t < len0) {                      // block-uniform guard
                    float em0 = emb0[d];
                    int tf0 = (t + 8 < len0) ? (t + 8) : (len0 - 1);
                    emb0[d] = fbr0[(size_t)tf0 * KK];
                    float em1 = emb1[d];
                    int tf1 = (t + 8 < len1) ? (t + 8) : (len1 - 1);
                    emb1[d] = fbr1[(size_t)tf1 * KK];
                    bool run1 = t < len1;

                    int cur = t & 1, nxt = cur ^ 1;
                    float Sn0 = As[0][nxt];
                    float Sn1 = As[1][nxt];
                    float fac0 = __expf(em0 + Mj_mine + A0 - Sn0);
                    float fac1 = __expf(em1 + Mj_mine + A1 - Sn1);
                    // issue all 4 LDS reads back-to-back (latencies overlap)
                    const v4f* xp0 = (const v4f*)(xs[0][cur] + xoff);
                    const v4f* xp1 = (const v4f*)(xs[1][cur] + xoff);
                    v4f xA[2], xB[2];
                    xA[0] = xp0[0]; xB[0] = xp0[1];
                    xA[1] = xp1[0]; xB[1] = xp1[1];

                    float acc[2][4];
#pragma unroll
                    for (int s = 0; s < 2; s++) {
#pragma unroll
                        for (int r = 0; r < 4; r++) {
                            float a = 0.f;
                            a = fmaf(Erow[8 * r + 0], xA[s].x, a);
                            a = fmaf(Erow[8 * r + 1], xA[s].y, a);
                            a = fmaf(Erow[8 * r + 2], xA[s].z, a);
                            a = fmaf(Erow[8 * r + 3], xA[s].w, a);
                            a = fmaf(Erow[8 * r + 4], xB[s].x, a);
                            a = fmaf(Erow[8 * r + 5], xB[s].y, a);
                            a = fmaf(Erow[8 * r + 6], xB[s].z, a);
                            a = fmaf(Erow[8 * r + 7], xB[s].w, a);
                            acc[s][r] = a;
                        }
                    }
                    float kk[2];
#pragma unroll
                    for (int s = 0; s < 2; s++) {
                        float k0 = b0 ? acc[s][2] : acc[s][0];
                        float k1 = b0 ? acc[s][3] : acc[s][1];
                        float s0 = b0 ? acc[s][0] : acc[s][2];
                        float s1 = b0 ? acc[s][1] : acc[s][3];
                        k0 += dpp_movf<0xB1>(s0);
                        k1 += dpp_movf<0xB1>(s1);
                        float km = b1 ? k1 : k0;
                        float sm = b1 ? k0 : k1;
                        km += dpp_movf<0x4E>(sm);
                        km += dpp_movf<0x124>(km);   // row_ror:4
                        km += dpp_movf<0x128>(km);   // row_ror:8
                        kk[s] = km;
                    }
                    if (writer) {
                        xs[0][nxt][xw] = kk[0] * fac0;
                        if (run1) xs[1][nxt][xw] = kk[1] * fac1;
                    }
                    alpha0 = em0 + Mj_mine + A0 + __logf(kk[0]);
                    A0 = Sn0;
                    if (run1) {
                        alpha1 = em1 + Mj_mine + A1 + __logf(kk[1]);
                        A1 = Sn1;
                    }
                    if (tid == 0) {
                        As[0][cur] = alpha0;
                        if (run1) As[1][cur] = alpha1;
                    }
                    STEP_BARRIER();
                }
            }
        }

        // terminal logsumexp_j( alpha_s[j] + trans[STOP,j] ) for s = 0,1
        float tstop = trans[TAG_STOP * KK + row_mine];
#pragma unroll
        for (int s = 0; s < 2; s++) {
            float alf = s ? alpha1 : alpha0;
            int bs = s ? b1i : b0i;
            float term = writer ? (alf + tstop) : -1e30f;
            float m = term;
#pragma unroll
            for (int off = 32; off >= 1; off >>= 1) m = fmaxf(m, __shfl_xor(m, off));
            float sv = writer ? __expf(term - m) : 0.f;
#pragma unroll
            for (int off = 32; off >= 1; off >>= 1) sv += __shfl_xor(sv, off);
            if (l == 0) { redm[w] = m; reds[w] = sv; }
            __syncthreads();
            if (tid == 0) {
                float M2 = redm[0];
                for (int i = 1; i < 8; i++) M2 = fmaxf(M2, redm[i]);
                float S2 = 0.f;
                for (int i = 0; i < 8; i++) S2 += reds[i] * __expf(redm[i] - M2);
                fwd_out[bs] = M2 + __logf(S2);
            }
            __syncthreads();   // protect redm/reds reuse for s=1
        }
    } else {
        // ---------------- gold path ----------------
        int b = blockIdx.x - BB / 2;
        int len = lengths[b];
        const int* tg = tags + (size_t)b * TT;
        const float* fb = feats + (size_t)b * TT * KK;
        float acc = 0.f;
        for (int i = tid; i <= len; i += 512) {
            int from = (i == 0) ? TAG_START : tg[i - 1];
            int to = (i < len) ? tg[i] : TAG_STOP;
            acc += trans[to * KK + from];
        }
        for (int t = tid; t < len; t += 512)
            acc += fb[(size_t)t * KK + tg[t]];
        __shared__ float sred[8];
#pragma unroll
        for (int off = 32; off >= 1; off >>= 1) acc += __shfl_xor(acc, off);
        if ((tid & 63) == 0) sred[tid >> 6] = acc;
        __syncthreads();
        if (tid == 0) {
            float s = 0.f;
            for (int i = 0; i < 8; i++) s += sred[i];
            gold_out[b] = s;
        }
    }
}

__global__ __launch_bounds__(512) void final_kernel(const float* __restrict__ fwd_s,
                                                    const float* __restrict__ gold_s,
                                                    float* __restrict__ out) {
    int tid = threadIdx.x;
    float v = fabsf(fwd_s[tid] - gold_s[tid]);
#pragma unroll
    for (int off = 32; off >= 1; off >>= 1) v += __shfl_xor(v, off);
    __shared__ float sred[8];
    if ((tid & 63) == 0) sred[tid >> 6] = v;
    __syncthreads();
    if (tid == 0) {
        float s = 0.f;
        for (int i = 0; i < 8; i++) s += sred[i];
        out[0] = s / (float)BB;
    }
}

extern "C" void kernel_launch(void* const* d_in, const int* in_sizes, int n_in,
                              void* d_out, int out_size, void* d_ws, size_t ws_size,
                              hipStream_t stream) {
    const float* feats = (const float*)d_in[0];
    const float* trans = (const float*)d_in[1];
    const int* tags = (const int*)d_in[2];
    const int* lengths = (const int*)d_in[3];

    float* ws = (float*)d_ws;
    float* fwdv = ws;
    float* goldv = ws + BB;
    int* order = (int*)(ws + 2 * BB);

    order_kernel<<<1, 512, 0, stream>>>(lengths, order);
    // blocks 0..255: paired forward; 256..767: gold
    fused_kernel<<<BB / 2 + BB, 512, 0, stream>>>(feats, trans, tags, lengths,
                                                  order, fwdv, goldv);
    final_kernel<<<1, 512, 0, stream>>>(fwdv, goldv, (float*)d_out);
}

// Round 7
// 316.620 us; speedup vs baseline: 1.3650x; 1.3650x over previous
//
#include <hip/hip_runtime.h>
#include <math.h>

#define KK 128
#define TT 512
#define BB 512
#define TAG_START 126
#define TAG_STOP 127

typedef float v4f __attribute__((ext_vector_type(4)));
typedef float v2f __attribute__((ext_vector_type(2)));

// x layout: chunk c (cols 8c..8c+7) at float offset 8c + 4*(c>>2); tag j at
// XI(j) = j + 4*(j>>5). Max XI(127)=139.
#define XI(j) ((j) + (((j) >> 5) << 2))

// DPP move (VALU pipe): quad_perm xor1=0xB1, xor2=0x4E; row_ror:4=0x124,
// row_ror:8=0x128 (rotation within 16-lane DPP rows).
template <int CTRL>
__device__ __forceinline__ float dpp_movf(float x) {
    return __int_as_float(
        __builtin_amdgcn_update_dpp(0, __float_as_int(x), CTRL, 0xF, 0xF, true));
}

// lgkmcnt-only barrier: LDS handoff needs lgkm drain; global prefetch loads
// stay in flight (per-thread register dests, no cross-thread hazard).
#define STEP_BARRIER() asm volatile("s_waitcnt lgkmcnt(0)\n\ts_barrier" ::: "memory")

// ws layout (1536 words): floats fwd [0,512), gold [512,1024); ints order [1024,1536)

// Descending-length rank: order[r] = seq index with rank r (longest dispatch first).
__global__ __launch_bounds__(512) void order_kernel(const int* __restrict__ lengths,
                                                    int* __restrict__ order) {
    __shared__ int L[BB];
    int tid = threadIdx.x;
    L[tid] = lengths[tid];
    __syncthreads();
    int mylen = L[tid];
    int r = 0;
    for (int i = 0; i < BB; i++) {
        int li = L[i];
        r += (li > mylen) || (li == mylen && i < tid);
    }
    order[r] = tid;
}

// Blocks 0..511: ONE sequence per block, split in half by associativity:
//   z(t+1) = D(t)·W·z(t), D(t)=diag(e^emit(t)) is data-independent of z, so
//   score = log(u^T · [prod t=len-1..m] D(t)W · [prod t=m-1..0] D(t)W · z0)
//   = LSE_k(alpha_m[k] + beta_m[k]).  Waves 0-3: forward half (m = len/2
//   steps). Waves 4-7: backward half v^T <- v^T D(t)W from u=e^trans[STOP,:]
//   (nb = len-m rounds), on E^T fragments. One barrier per round; rounds =
//   ceil(len/2) -- HALF the serial critical path (R1/R3/R5 all measured
//   makespan = 512 x solo per-step chain latency; this attacks round count).
// Backward emission ring (bug fixed vs previous attempt): slot d=i&3 holds
//   em(len-2-i); init em(len-2-d); refill em(len-2-(i+4)). Init vector uses
//   separate em(len-1) scalars.
// Per-thread (within its 4-wave group): 8 rows x 8 cols of E in regs;
// reduce = quad_perm xor1/xor2 halving (-> 2 rows/lane) + ror4/ror8 replica
// sums; writer lanes (l&12)==0 write 2 adjacent rows as one b64.
// Blocks 512..1023: gold score for seq blockIdx-512.
__global__ __launch_bounds__(512, 4) void fused_kernel(
    const float* __restrict__ feats, const float* __restrict__ trans,
    const int* __restrict__ tags, const int* __restrict__ lengths,
    const int* __restrict__ order,
    float* __restrict__ fwd_out, float* __restrict__ gold_out) {
    int tid = threadIdx.x;
    int w = tid >> 6;
    int l = tid & 63;

    if (blockIdx.x < BB) {
        // ---------------- forward+backward split ----------------
        int b = order[blockIdx.x];
        int len = lengths[b];
        int m = len >> 1;       // forward steps
        int nb = len - m;       // backward steps = rounds (nb >= m)

        __shared__ __align__(16) float xsf[2][160];
        __shared__ __align__(16) float xsb[2][160];
        __shared__ float Asf[2], Asb[2];
        __shared__ float sh_a[KK], sh_b[KK];
        __shared__ float redm[8], reds[8];

        bool is_fwd = (w < 4);
        int wg = w & 3;
        int g = (l >> 4) & 3;
        int c = l & 15;
        bool b0 = (l & 1) != 0;
        bool b1 = (l & 2) != 0;
        int base = 32 * wg + 8 * g;                   // first of 8 rows
        int rA = base + (b0 ? 4 : 0) + (b1 ? 2 : 0);  // first written row
        int xoff = 8 * c + 4 * (c >> 2);
        bool writer = (l & 12) == 0;

        // ---- E fragment: 8 rows x 8 cols (fwd: rows of trans; bwd: cols) ----
        float Ef[64];
        if (is_fwd) {
#pragma unroll
            for (int r = 0; r < 8; r++) {
                v4f lo = *(const v4f*)(trans + (base + r) * KK + 8 * c);
                v4f hi = *(const v4f*)(trans + (base + r) * KK + 8 * c + 4);
                Ef[8 * r + 0] = lo.x; Ef[8 * r + 1] = lo.y;
                Ef[8 * r + 2] = lo.z; Ef[8 * r + 3] = lo.w;
                Ef[8 * r + 4] = hi.x; Ef[8 * r + 5] = hi.y;
                Ef[8 * r + 6] = hi.z; Ef[8 * r + 7] = hi.w;
            }
        } else {
#pragma unroll
            for (int r = 0; r < 8; r++)
#pragma unroll
                for (int cc = 0; cc < 8; cc++)
                    Ef[8 * r + cc] = trans[(8 * c + cc) * KK + (base + r)];
        }
        // per-row max over the full row (reduce across 16 chunk lanes)
        float Mj[8];
#pragma unroll
        for (int r = 0; r < 8; r++) {
            float mm = Ef[8 * r];
#pragma unroll
            for (int j = 1; j < 8; j++) mm = fmaxf(mm, Ef[8 * r + j]);
#pragma unroll
            for (int off = 1; off <= 8; off <<= 1)
                mm = fmaxf(mm, __shfl_xor(mm, off));
            Mj[r] = mm;
        }
#pragma unroll
        for (int r = 0; r < 8; r++)
#pragma unroll
            for (int j = 0; j < 8; j++)
                Ef[8 * r + j] = __expf(Ef[8 * r + j] - Mj[r]);
        float MjA = b0 ? (b1 ? Mj[6] : Mj[4]) : (b1 ? Mj[2] : Mj[0]);
        float MjB = b0 ? (b1 ? Mj[7] : Mj[5]) : (b1 ? Mj[3] : Mj[1]);

        // emissions for the 2 written rows, rolling depth-4 ring
        const float* fA = feats + (size_t)b * TT * KK + rA;
        const float* fB = fA + 1;
        float embA[4], embB[4];
        float emIA = 0.f, emIB = 0.f;
        if (is_fwd) {
            int mm1 = (m > 0) ? (m - 1) : 0;
#pragma unroll
            for (int d = 0; d < 4; d++) {
                int tf = (d < m) ? d : mm1;
                embA[d] = fA[(size_t)tf * KK];
                embB[d] = fB[(size_t)tf * KK];
            }
        } else {
            emIA = fA[(size_t)(len - 1) * KK];
            emIB = fB[(size_t)(len - 1) * KK];
#pragma unroll
            for (int d = 0; d < 4; d++) {
                int t = len - 2 - d;
                if (t < 0) t = 0;
                embA[d] = fA[(size_t)t * KK];
                embB[d] = fB[(size_t)t * KK];
            }
        }

        // log-state (used directly if the side runs 0 steps)
        float alphaA, alphaB;
        if (is_fwd) {
            alphaA = (rA == TAG_START) ? 0.f : -1e30f;
            alphaB = (rA + 1 == TAG_START) ? 0.f : -1e30f;
        } else {
            alphaA = -1e30f; alphaB = -1e30f;
        }

        // init state vectors
        if (is_fwd) {
            if (writer) {
                v2f x0;
                x0.x = (rA == TAG_START) ? 1.f : 0.f;
                x0.y = (rA + 1 == TAG_START) ? 1.f : 0.f;
                *(v2f*)&xsf[0][XI(rA)] = x0;
            }
            if (tid == 0) { Asf[0] = 0.f; Asf[1] = 0.f; }
        } else {
            if (writer) {
                // v~init = u .* e^{em(len-1)} = exp(trans[STOP,k] + em(len-1)[k])
                v2f x0;
                x0.x = __expf(trans[TAG_STOP * KK + rA] + emIA);
                x0.y = __expf(trans[TAG_STOP * KK + rA + 1] + emIB);
                *(v2f*)&xsb[0][XI(rA)] = x0;
            }
            if (tid == 256) { Asb[0] = 0.f; Asb[1] = 0.f; }
        }
        float A = 0.f;
        __syncthreads();

        for (int i0 = 0; i0 < nb; i0 += 4) {
#pragma unroll
            for (int d = 0; d < 4; d++) {
                int i = i0 + d;
                if (i < nb) {                      // block-uniform
                    if (is_fwd) {
                        if (i < m) {               // block-uniform (m<=nb)
                            float emA = embA[d], emB = embB[d];
                            int tf = (i + 4 < m) ? (i + 4) : (m - 1);
                            embA[d] = fA[(size_t)tf * KK];
                            embB[d] = fB[(size_t)tf * KK];

                            int cur = i & 1, nxt = cur ^ 1;
                            float Sn = Asf[nxt];
                            float facA = __expf(emA + MjA + A - Sn);
                            float facB = __expf(emB + MjB + A - Sn);
                            const v4f* xp = (const v4f*)(xsf[cur] + xoff);
                            v4f xa = xp[0], xb = xp[1];
                            float acc[8];
#pragma unroll
                            for (int r = 0; r < 8; r++) {
                                float a = 0.f;
                                a = fmaf(Ef[8 * r + 0], xa.x, a);
                                a = fmaf(Ef[8 * r + 1], xa.y, a);
                                a = fmaf(Ef[8 * r + 2], xa.z, a);
                                a = fmaf(Ef[8 * r + 3], xa.w, a);
                                a = fmaf(Ef[8 * r + 4], xb.x, a);
                                a = fmaf(Ef[8 * r + 5], xb.y, a);
                                a = fmaf(Ef[8 * r + 6], xb.z, a);
                                a = fmaf(Ef[8 * r + 7], xb.w, a);
                                acc[r] = a;
                            }
                            float k4[4];
#pragma unroll
                            for (int ii = 0; ii < 4; ii++) {
                                float kp = b0 ? acc[ii + 4] : acc[ii];
                                float sp = b0 ? acc[ii] : acc[ii + 4];
                                k4[ii] = kp + dpp_movf<0xB1>(sp);
                            }
                            float k0, k1;
                            {
                                float kp = b1 ? k4[2] : k4[0];
                                float sp = b1 ? k4[0] : k4[2];
                                k0 = kp + dpp_movf<0x4E>(sp);
                            }
                            {
                                float kp = b1 ? k4[3] : k4[1];
                                float sp = b1 ? k4[1] : k4[3];
                                k1 = kp + dpp_movf<0x4E>(sp);
                            }
                            k0 += dpp_movf<0x124>(k0);
                            k0 += dpp_movf<0x128>(k0);
                            k1 += dpp_movf<0x124>(k1);
                            k1 += dpp_movf<0x128>(k1);
                            if (writer) {
                                v2f xn; xn.x = k0 * facA; xn.y = k1 * facB;
                                *(v2f*)&xsf[nxt][XI(rA)] = xn;
                            }
                            if (tid == 0) Asf[cur] = emA + MjA + A + __logf(k0);
                            if (i == m - 1) {      // final fwd round: true alphas
                                alphaA = emA + MjA + A + __logf(k0);
                                alphaB = emB + MjB + A + __logf(k1);
                            }
                            A = Sn;
                        }
                    } else {
                        // round i processes t = len-1-i; needs em(t-1)=em(len-2-i)
                        float emNA = embA[d];
                        float emNB = embB[d];
                        {   // refill slot d for round i+4: em(len-2-(i+4))
                            int tp = len - 6 - i;
                            if (tp < 0) tp = 0;
                            embA[d] = fA[(size_t)tp * KK];
                            embB[d] = fB[(size_t)tp * KK];
                        }
                        int cur = i & 1, nxt = cur ^ 1;
                        float Sn = Asb[nxt];
                        float facA = __expf(emNA + MjA + A - Sn);
                        float facB = __expf(emNB + MjB + A - Sn);
                        const v4f* xp = (const v4f*)(xsb[cur] + xoff);
                        v4f xa = xp[0], xb = xp[1];
                        float acc[8];
#pragma unroll
                        for (int r = 0; r < 8; r++) {
                            float a = 0.f;
                            a = fmaf(Ef[8 * r + 0], xa.x, a);
                            a = fmaf(Ef[8 * r + 1], xa.y, a);
                            a = fmaf(Ef[8 * r + 2], xa.z, a);
                            a = fmaf(Ef[8 * r + 3], xa.w, a);
                            a = fmaf(Ef[8 * r + 4], xb.x, a);
                            a = fmaf(Ef[8 * r + 5], xb.y, a);
                            a = fmaf(Ef[8 * r + 6], xb.z, a);
                            a = fmaf(Ef[8 * r + 7], xb.w, a);
                            acc[r] = a;
                        }
                        float k4[4];
#pragma unroll
                        for (int ii = 0; ii < 4; ii++) {
                            float kp = b0 ? acc[ii + 4] : acc[ii];
                            float sp = b0 ? acc[ii] : acc[ii + 4];
                            k4[ii] = kp + dpp_movf<0xB1>(sp);
                        }
                        float k0, k1;
                        {
                            float kp = b1 ? k4[2] : k4[0];
                            float sp = b1 ? k4[0] : k4[2];
                            k0 = kp + dpp_movf<0x4E>(sp);
                        }
                        {
                            float kp = b1 ? k4[3] : k4[1];
                            float sp = b1 ? k4[1] : k4[3];
                            k1 = kp + dpp_movf<0x4E>(sp);
                        }
                        k0 += dpp_movf<0x124>(k0);
                        k0 += dpp_movf<0x128>(k0);
                        k1 += dpp_movf<0x124>(k1);
                        k1 += dpp_movf<0x128>(k1);
                        if (writer) {
                            v2f xn; xn.x = k0 * facA; xn.y = k1 * facB;
                            *(v2f*)&xsb[nxt][XI(rA)] = xn;
                        }
                        if (tid == 256) Asb[cur] = MjA + A + __logf(k0);
                        if (i == nb - 1) {         // final bwd round: true betas (no em)
                            alphaA = MjA + A + __logf(k0);
                            alphaB = MjB + A + __logf(k1);
                        }
                        A = Sn;
                    }
                    STEP_BARRIER();
                }
            }
        }

        // ---- combine: score = LSE_k(alpha_m[k] + beta_m[k]) ----
        if (writer) {
            if (is_fwd) { sh_a[rA] = alphaA; sh_a[rA + 1] = alphaB; }
            else        { sh_b[rA] = alphaA; sh_b[rA + 1] = alphaB; }
        }
        __syncthreads();
        float term = (tid < KK) ? (sh_a[tid] + sh_b[tid]) : -1e30f;
        float mx = term;
#pragma unroll
        for (int off = 32; off >= 1; off >>= 1) mx = fmaxf(mx, __shfl_xor(mx, off));
        float s = (tid < KK) ? __expf(term - mx) : 0.f;
#pragma unroll
        for (int off = 32; off >= 1; off >>= 1) s += __shfl_xor(s, off);
        if (l == 0) { redm[w] = mx; reds[w] = s; }
        __syncthreads();
        if (tid == 0) {
            float M2 = redm[0];
            for (int i = 1; i < 8; i++) M2 = fmaxf(M2, redm[i]);
            float S2 = 0.f;
            for (int i = 0; i < 8; i++) S2 += reds[i] * __expf(redm[i] - M2);
            fwd_out[b] = M2 + __logf(S2);
        }
    } else {
        // ---------------- gold path ----------------
        int b = blockIdx.x - BB;
        int len = lengths[b];
        const int* tg = tags + (size_t)b * TT;
        const float* fb = feats + (size_t)b * TT * KK;
        float acc = 0.f;
        for (int i = tid; i <= len; i += 512) {
            int from = (i == 0) ? TAG_START : tg[i - 1];
            int to = (i < len) ? tg[i] : TAG_STOP;
            acc += trans[to * KK + from];
        }
        for (int t = tid; t < len; t += 512)
            acc += fb[(size_t)t * KK + tg[t]];
        __shared__ float sred[8];
#pragma unroll
        for (int off = 32; off >= 1; off >>= 1) acc += __shfl_xor(acc, off);
        if ((tid & 63) == 0) sred[tid >> 6] = acc;
        __syncthreads();
        if (tid == 0) {
            float s = 0.f;
            for (int i = 0; i < 8; i++) s += sred[i];
            gold_out[b] = s;
        }
    }
}

__global__ __launch_bounds__(512) void final_kernel(const float* __restrict__ fwd_s,
                                                    const float* __restrict__ gold_s,
                                                    float* __restrict__ out) {
    int tid = threadIdx.x;
    float v = fabsf(fwd_s[tid] - gold_s[tid]);
#pragma unroll
    for (int off = 32; off >= 1; off >>= 1) v += __shfl_xor(v, off);
    __shared__ float sred[8];
    if ((tid & 63) == 0) sred[tid >> 6] = v;
    __syncthreads();
    if (tid == 0) {
        float s = 0.f;
        for (int i = 0; i < 8; i++) s += sred[i];
        out[0] = s / (float)BB;
    }
}

extern "C" void kernel_launch(void* const* d_in, const int* in_sizes, int n_in,
                              void* d_out, int out_size, void* d_ws, size_t ws_size,
                              hipStream_t stream) {
    const float* feats = (const float*)d_in[0];
    const float* trans = (const float*)d_in[1];
    const int* tags = (const int*)d_in[2];
    const int* lengths = (const int*)d_in[3];

    float* ws = (float*)d_ws;
    float* fwdv = ws;
    float* goldv = ws + BB;
    int* order = (int*)(ws + 2 * BB);

    order_kernel<<<1, 512, 0, stream>>>(lengths, order);
    fused_kernel<<<2 * BB, 512, 0, stream>>>(feats, trans, tags, lengths, order,
                                             fwdv, goldv);
    final_kernel<<<1, 512, 0, stream>>>(fwdv, goldv, (float*)d_out);
}